// Round 16
// baseline (2803.117 us; speedup 1.0000x reference)
//
#include <hip/hip_runtime.h>
#include <hip/hip_bf16.h>
#include <cstddef>
#include <cstdint>

#define BB   32
#define TT   2048
#define DIN  512
#define DD   512
#define NN   3072
#define PW   3072    // proj row width (f16): col = p*1024 + d*2 + q, gate k=2p+q
#define PF   16      // scan prefetch depth (steps)
#define SCANBLKS 32  // scan blocks (512 thr each) leading the fused grid

#define BMT 256      // GEMM tile M
#define BNT 256      // GEMM tile N
#define BKT 32       // GEMM K-tile
#define NKT (DIN / BKT)   // 16 K-tiles

typedef __attribute__((ext_vector_type(4))) float f32x4;
typedef __attribute__((ext_vector_type(8))) short s16x8;

// ---------------------------------------------------------------------------
// helpers
// ---------------------------------------------------------------------------
__device__ __forceinline__ void gl2lds16(const void* g, void* l) {
    __builtin_amdgcn_global_load_lds(
        (const __attribute__((address_space(1))) unsigned*)g,
        (__attribute__((address_space(3))) unsigned*)l, 16, 0, 0);
}

__device__ __forceinline__ unsigned short bfr(float f) {   // f32 -> bf16 RNE
    unsigned u = __float_as_uint(f);
    u += 0x7fffu + ((u >> 16) & 1u);
    return (unsigned short)(u >> 16);
}

__device__ __forceinline__ float ftanh(float x) {
    return 1.f - 2.f * __builtin_amdgcn_rcpf(1.f + __builtin_amdgcn_exp2f(x * 2.885390082f));
}

__device__ __forceinline__ float h2lo(unsigned u) {
    return (float)__builtin_bit_cast(_Float16, (unsigned short)(u & 0xffffu));
}
__device__ __forceinline__ float h2hi(unsigned u) {
    return (float)__builtin_bit_cast(_Float16, (unsigned short)(u >> 16));
}

// ---------------------------------------------------------------------------
// convert x [B][T][DIN] f32 -> x2 [(t*32+b)][DIN] bf16
// ---------------------------------------------------------------------------
__global__ __launch_bounds__(256) void convert_x(
    const float* __restrict__ x, unsigned short* __restrict__ x2)
{
    const int total4 = BB * TT * DIN / 4;
    for (int idx = blockIdx.x * 256 + threadIdx.x; idx < total4;
         idx += gridDim.x * 256) {
        int e = idx * 4;
        int b = e >> 20;
        int t = (e >> 9) & 2047;
        int i = e & 511;
        float4 v = *(const float4*)(x + (size_t)e);
        ushort4 o;
        o.x = bfr(v.x); o.y = bfr(v.y); o.z = bfr(v.z); o.w = bfr(v.w);
        *(ushort4*)(x2 + ((size_t)((t << 5) | b) << 9) + i) = o;
    }
}

// ---------------------------------------------------------------------------
// convert W: W2 row c (pair-planar): p = c>>10, d = (c&1023)>>1, q = c&1,
// gate k = 2p+q, original W row o = k*512 + d. bias permuted likewise.
// ---------------------------------------------------------------------------
__global__ __launch_bounds__(128) void convert_w(
    const float* __restrict__ W, const float* __restrict__ bias,
    unsigned short* __restrict__ W2, float* __restrict__ bias2)
{
    int c = blockIdx.x;            // 0..3071
    int p = c >> 10, d = (c & 1023) >> 1, q = c & 1;
    int o = ((2 * p + q) << 9) + d;
    const float* src = W + (size_t)o * DIN;
    unsigned short* dst = W2 + (size_t)c * DIN;
    int i = threadIdx.x * 4;
    float4 v = *(const float4*)(src + i);
    ushort4 u;
    u.x = bfr(v.x); u.y = bfr(v.y); u.z = bfr(v.z); u.w = bfr(v.w);
    *(ushort4*)(dst + i) = u;
    if (threadIdx.x == 0) bias2[c] = bias[o];
}

// ---------------------------------------------------------------------------
// Fused per-chunk kernel.
//  blocks [0,32): scan of chunk i-1 (projSrc)
//  blocks [32, 32+nG): 256x256 8-wave GEMM, BK=32, DOUBLE-buffered 64KB LDS
//    -> 2 blocks/CU (16 waves/CU): cross-BLOCK overlap absorbs the per-K-tile
//    drain (m97/m114 mechanism). stage(kt+1) at top of kt; vmcnt(0)+barrier
//    at the boundary (classic 2-phase loop, drain hidden by the other block).
//  Epilogue: wave-local LDS transpose (overlays slot 0; last read kt=14,
//  boundary barrier passed) -> 16B/lane full-line proj stores.
// ---------------------------------------------------------------------------
__global__ __launch_bounds__(512, 4) void fused_chunk(
    const unsigned short* __restrict__ x2,    // [T*32][512] bf16
    const unsigned short* __restrict__ W2,    // [3072][512] bf16 (permuted)
    const float* __restrict__ bias2,          // [3072] (permuted)
    _Float16* __restrict__ projDst,           // [Tcg*32][PW]
    const _Float16* __restrict__ projSrc,     // [Tcs*32][PW]
    const float* __restrict__ h0, const float* __restrict__ s0,
    float* __restrict__ outH, float* __restrict__ outS,
    int t0g, int Tcg, int t0s, int Tcs)
{
    // slot s (s=0,1): A (256x32) at lds + s*16384, B at +8192 (shorts); 64 KB
    __shared__ unsigned short lds[2 * 16384];

    if (blockIdx.x < SCANBLKS) {
        // ------------------------- scan of chunk i-1 -------------------------
        if (t0s < 0) return;
        const int gid = blockIdx.x * 512 + threadIdx.x;   // 0..16383
        const int b   = gid >> 9;
        const int d   = gid & 511;

        float h, s;
        if (t0s == 0) { h = h0[gid]; s = s0[gid]; }
        else {
            h = outH[((size_t)b * TT + (t0s - 1)) * DD + d];
            s = outS[gid];
        }

        const unsigned* pu = (const unsigned*)(projSrc + (size_t)b * PW + d * 2);
        const size_t tstr = (size_t)BB * PW / 2;   // uints per step
        float* oH = outH + ((size_t)b * TT + t0s) * DD + d;

        unsigned bufA[PF][3], bufB[PF][3];
        #pragma unroll
        for (int u = 0; u < PF; ++u)
            #pragma unroll
            for (int p = 0; p < 3; ++p)
                bufA[u][p] = pu[(size_t)u * tstr + p * 512];

        for (int tb = 0; tb < Tcs; tb += 2 * PF) {
            #pragma unroll
            for (int u = 0; u < PF; ++u) {
                int t = tb + PF + u; if (t > Tcs - 1) t = Tcs - 1;
                #pragma unroll
                for (int p = 0; p < 3; ++p)
                    bufB[u][p] = pu[(size_t)t * tstr + p * 512];
            }
            #pragma unroll
            for (int u = 0; u < PF; ++u) {
                float a0 = h2lo(bufA[u][0]), a1 = h2hi(bufA[u][0]);
                float t2 = h2lo(bufA[u][1]), a3 = h2hi(bufA[u][1]);
                float a4 = h2lo(bufA[u][2]), z5 = h2hi(bufA[u][2]);
                s = __builtin_fmaf(a0, s, a1 * t2);
                h = __builtin_fmaf(a3, h, a4 * ftanh(z5 + s));
                oH[(size_t)(tb + u) * DD] = h;
            }
            #pragma unroll
            for (int u = 0; u < PF; ++u) {
                int t = tb + 2 * PF + u; if (t > Tcs - 1) t = Tcs - 1;
                #pragma unroll
                for (int p = 0; p < 3; ++p)
                    bufA[u][p] = pu[(size_t)t * tstr + p * 512];
            }
            #pragma unroll
            for (int u = 0; u < PF; ++u) {
                float a0 = h2lo(bufB[u][0]), a1 = h2hi(bufB[u][0]);
                float t2 = h2lo(bufB[u][1]), a3 = h2hi(bufB[u][1]);
                float a4 = h2lo(bufB[u][2]), z5 = h2hi(bufB[u][2]);
                s = __builtin_fmaf(a0, s, a1 * t2);
                h = __builtin_fmaf(a3, h, a4 * ftanh(z5 + s));
                oH[(size_t)(tb + PF + u) * DD] = h;
            }
        }
        outS[gid] = s;
        return;
    }

    // ----------------------------- GEMM of chunk i ---------------------------
    if (t0g < 0) return;
    const unsigned nwg = gridDim.x - SCANBLKS;
    const unsigned fb  = blockIdx.x - SCANBLKS;
    const unsigned qq  = nwg >> 3, rr8 = nwg & 7;
    const unsigned xcd = fb & 7, sid = fb >> 3;
    const unsigned work = (xcd < rr8 ? xcd * (qq + 1)
                                     : rr8 * (qq + 1) + (xcd - rr8) * qq) + sid;
    const int bx = (int)(work % (NN / BNT));    // 12 col tiles
    const int by = (int)(work / (NN / BNT));

    const int tid  = threadIdx.x;
    const int row0 = by * BMT;                  // chunk-local
    const int col0 = bx * BNT;
    const size_t growA = (size_t)t0g * BB + row0;

    const int lane = tid & 63;
    const int wv   = tid >> 6;       // 0..7
    const int wm   = wv >> 2;        // 0..1  (M half)
    const int wn   = wv & 3;         // 0..3  (N quarter)
    const int lr   = lane & 15;
    const int lq   = lane >> 4;

    auto stageA = [&](int s, int kt) {
        unsigned short* Ab = lds + s * 16384;
        const int k0 = kt * BKT;
        #pragma unroll
        for (int a = 0; a < 2; ++a) {
            int cid = a * 512 + tid;        // 0..1023
            int rt  = cid >> 2;             // row
            int cp  = cid & 3;              // 16B chunk in row
            gl2lds16(x2 + (growA + rt) * DIN + k0 + cp * 8, Ab + cid * 8);
        }
    };
    auto stageB = [&](int s, int kt) {
        unsigned short* Bb = lds + s * 16384 + 8192;
        const int k0 = kt * BKT;
        #pragma unroll
        for (int a = 0; a < 2; ++a) {
            int cid = a * 512 + tid;
            int rt  = cid >> 2;
            int cp  = cid & 3;
            gl2lds16(W2 + (size_t)(col0 + rt) * DIN + k0 + cp * 8, Bb + cid * 8);
        }
    };

    f32x4 acc[8][4] = {};

    // prologue: stage K-tile 0 into slot 0, drain, barrier
    stageA(0, 0); stageB(0, 0);
    asm volatile("s_waitcnt vmcnt(0)" ::: "memory");
    __builtin_amdgcn_s_barrier();

    #pragma unroll
    for (int kt = 0; kt < NKT; ++kt) {
        const unsigned short* Ab = lds + (kt & 1) * 16384;
        const unsigned short* Bb = Ab + 8192;
        const bool st = (kt + 1) < NKT;

        // stage next K-tile into the other slot (reads of it ended last iter)
        if (st) { stageA((kt + 1) & 1, kt + 1); stageB((kt + 1) & 1, kt + 1); }

        s16x8 bv[4], av[8];
        #pragma unroll
        for (int j = 0; j < 4; ++j) {
            int col = wn * 64 + j * 16 + lr;
            bv[j] = *(const s16x8*)(Bb + col * BKT + lq * 8);
        }
        #pragma unroll
        for (int m = 0; m < 8; ++m) {
            int row = wm * 128 + m * 16 + lr;
            av[m] = *(const s16x8*)(Ab + row * BKT + lq * 8);
        }

        __builtin_amdgcn_s_setprio(1);
        #pragma unroll
        for (int m = 0; m < 8; ++m)
            #pragma unroll
            for (int j = 0; j < 4; ++j)
                acc[m][j] = __builtin_amdgcn_mfma_f32_16x16x32_bf16(
                    bv[j], av[m], acc[m][j], 0, 0, 0);
        __builtin_amdgcn_s_setprio(0);

        // boundary: next tile landed for ALL waves; drain hidden by the
        // co-resident block on this CU (2 blocks/CU at 64KB LDS).
        if (st) {
            asm volatile("s_waitcnt vmcnt(0)" ::: "memory");
            __builtin_amdgcn_s_barrier();
        }
    }

    // ---- epilogue: bias + activation, wave-local LDS transpose, ----
    // ---- 16B/lane full-line stores. Overlays slot 0 (last read kt=14;
    // ---- boundary barrier at end of kt=14 passed; kt=15 reads slot 1). ----
    const int p = col0 >> 10;
    const bool evenTanh = (p == 1);
    const bool oddIdent = (p == 2);
    const float mEven = evenTanh ? 2.885390082f : -1.442695041f;

    char* epi = (char*)lds + wv * 2304;   // 16 rows x 144 B, per-wave private
    const int colw = col0 + wn * 64;
    const int l8 = lane & 7, lh = lane >> 3;

    #pragma unroll
    for (int m = 0; m < 8; ++m) {
        // compute + write 8B per j into this wave's private slot
        #pragma unroll
        for (int j = 0; j < 4; ++j) {
            float4 bc = *(const float4*)(bias2 + colw + j * 16 + lq * 4);
            float z0 = acc[m][j][0] + bc.x;
            float z1 = acc[m][j][1] + bc.y;
            float z2 = acc[m][j][2] + bc.z;
            float z3 = acc[m][j][3] + bc.w;
            float e0 = __builtin_amdgcn_rcpf(1.f + __builtin_amdgcn_exp2f(z0 * mEven));
            float e2 = __builtin_amdgcn_rcpf(1.f + __builtin_amdgcn_exp2f(z2 * mEven));
            float v0 = evenTanh ? (1.f - 2.f * e0) : e0;
            float v2 = evenTanh ? (1.f - 2.f * e2) : e2;
            float v1 = oddIdent ? z1
                : __builtin_amdgcn_rcpf(1.f + __builtin_amdgcn_exp2f(z1 * -1.442695041f));
            float v3 = oddIdent ? z3
                : __builtin_amdgcn_rcpf(1.f + __builtin_amdgcn_exp2f(z3 * -1.442695041f));
            ushort4 o;
            o.x = __builtin_bit_cast(unsigned short, (_Float16)v0);
            o.y = __builtin_bit_cast(unsigned short, (_Float16)v1);
            o.z = __builtin_bit_cast(unsigned short, (_Float16)v2);
            o.w = __builtin_bit_cast(unsigned short, (_Float16)v3);
            *(ushort4*)(epi + lr * 144 + j * 32 + lq * 8) = o;
        }
        // read back row-contiguous, store 16B/lane (compiler inserts lgkmcnt)
        #pragma unroll
        for (int hh = 0; hh < 2; ++hh) {
            int rr = hh * 8 + lh;
            uint4 v = *(const uint4*)(epi + rr * 144 + l8 * 16);
            int g = row0 + wm * 128 + m * 16 + rr;
            *(uint4*)((char*)projDst + ((size_t)g * PW + colw + l8 * 8) * 2) = v;
        }
    }
}

// ---------------------------------------------------------------------------
extern "C" void kernel_launch(void* const* d_in, const int* in_sizes, int n_in,
                              void* d_out, int out_size, void* d_ws, size_t ws_size,
                              hipStream_t stream) {
    const float* x    = (const float*)d_in[0];
    const float* h0   = (const float*)d_in[1];
    const float* s0   = (const float*)d_in[2];
    const float* W    = (const float*)d_in[3];
    const float* bias = (const float*)d_in[4];

    float* outH = (float*)d_out;
    float* outS = outH + (size_t)BB * TT * DD;

    char* ws = (char*)d_ws;
    const size_t x2_bytes = (size_t)BB * TT * DIN * 2;       // 64 MB
    const size_t w2_bytes = (size_t)NN * DIN * 2;            // 3 MB
    const size_t b2_bytes = (size_t)NN * 4;
    unsigned short* x2    = (unsigned short*)ws;
    unsigned short* W2    = (unsigned short*)(ws + x2_bytes);
    float*          bias2 = (float*)(ws + x2_bytes + w2_bytes);

    const size_t fixed = x2_bytes + w2_bytes + b2_bytes;
    const size_t per_t = (size_t)BB * PW * 2;                // 192 KB / step
    size_t avail = ws_size > fixed ? ws_size - fixed : 0;
    int TcMax = (int)(avail / (2 * per_t));                  // ping-pong proj
    if (TcMax > 512) TcMax = 512;   // keep proj chunk L3-resident
    TcMax &= ~31;                   // multiple of 32 (scan 2*PF, M tile 256)
    if (TcMax < 32) TcMax = 32;

    _Float16* projA = (_Float16*)(ws + fixed);
    _Float16* projB = projA + (size_t)TcMax * BB * PW;

    convert_x<<<2048, 256, 0, stream>>>(x, x2);
    convert_w<<<NN, 128, 0, stream>>>(W, bias, W2, bias2);

    const int nC = (TT + TcMax - 1) / TcMax;
    int prevT0 = -1, prevTc = 0;
    const _Float16* prevProj = nullptr;

    for (int ci = 0; ci <= nC; ++ci) {
        const bool hasG = (ci < nC);
        int t0 = ci * TcMax;
        int Tc = 0;
        _Float16* dst = nullptr;
        int nG = 0;
        if (hasG) {
            Tc  = TT - t0; if (Tc > TcMax) Tc = TcMax;
            dst = (ci & 1) ? projB : projA;
            nG  = (NN / BNT) * (Tc * BB / BMT);
        }
        fused_chunk<<<dim3(SCANBLKS + nG), 512, 0, stream>>>(
            x2, W2, bias2, dst, prevProj, h0, s0, outH, outS,
            hasG ? t0 : -1, Tc, prevT0, prevTc);
        if (hasG) { prevProj = dst; prevT0 = t0; prevTc = Tc; }
    }
}

// Round 17
// 459.925 us; speedup vs baseline: 6.0947x; 6.0947x over previous
//
#include <hip/hip_runtime.h>
#include <hip/hip_bf16.h>
#include <cstddef>
#include <cstdint>

#define BB   32
#define TT   2048
#define DIN  512
#define DD   512
#define NN   3072
#define PW   3072    // proj row width (f16): col = p*1024 + d*2 + q, gate k=2p+q
#define PF   16      // scan prefetch depth (steps)
#define SCANBLKS 32  // scan blocks (512 thr each) leading the fused grid

#define BMT 256      // GEMM tile M
#define BNT 256      // GEMM tile N
#define BKT 32       // GEMM K-tile
#define NKT (DIN / BKT)   // 16 K-tiles

typedef __attribute__((ext_vector_type(4))) float f32x4;
typedef __attribute__((ext_vector_type(8))) short s16x8;

// ---------------------------------------------------------------------------
// helpers
// ---------------------------------------------------------------------------
__device__ __forceinline__ void gl2lds16(const void* g, void* l) {
    __builtin_amdgcn_global_load_lds(
        (const __attribute__((address_space(1))) unsigned*)g,
        (__attribute__((address_space(3))) unsigned*)l, 16, 0, 0);
}

__device__ __forceinline__ unsigned short bfr(float f) {   // f32 -> bf16 RNE
    unsigned u = __float_as_uint(f);
    u += 0x7fffu + ((u >> 16) & 1u);
    return (unsigned short)(u >> 16);
}

__device__ __forceinline__ float ftanh(float x) {
    return 1.f - 2.f * __builtin_amdgcn_rcpf(1.f + __builtin_amdgcn_exp2f(x * 2.885390082f));
}

__device__ __forceinline__ float h2lo(unsigned u) {
    return (float)__builtin_bit_cast(_Float16, (unsigned short)(u & 0xffffu));
}
__device__ __forceinline__ float h2hi(unsigned u) {
    return (float)__builtin_bit_cast(_Float16, (unsigned short)(u >> 16));
}

// ---------------------------------------------------------------------------
// convert x [B][T][DIN] f32 -> x2 [(t*32+b)][DIN] bf16
// ---------------------------------------------------------------------------
__global__ __launch_bounds__(256) void convert_x(
    const float* __restrict__ x, unsigned short* __restrict__ x2)
{
    const int total4 = BB * TT * DIN / 4;
    for (int idx = blockIdx.x * 256 + threadIdx.x; idx < total4;
         idx += gridDim.x * 256) {
        int e = idx * 4;
        int b = e >> 20;
        int t = (e >> 9) & 2047;
        int i = e & 511;
        float4 v = *(const float4*)(x + (size_t)e);
        ushort4 o;
        o.x = bfr(v.x); o.y = bfr(v.y); o.z = bfr(v.z); o.w = bfr(v.w);
        *(ushort4*)(x2 + ((size_t)((t << 5) | b) << 9) + i) = o;
    }
}

// ---------------------------------------------------------------------------
// convert W: W2 row c (pair-planar): p = c>>10, d = (c&1023)>>1, q = c&1,
// gate k = 2p+q, original W row o = k*512 + d. bias permuted likewise.
// ---------------------------------------------------------------------------
__global__ __launch_bounds__(128) void convert_w(
    const float* __restrict__ W, const float* __restrict__ bias,
    unsigned short* __restrict__ W2, float* __restrict__ bias2)
{
    int c = blockIdx.x;            // 0..3071
    int p = c >> 10, d = (c & 1023) >> 1, q = c & 1;
    int o = ((2 * p + q) << 9) + d;
    const float* src = W + (size_t)o * DIN;
    unsigned short* dst = W2 + (size_t)c * DIN;
    int i = threadIdx.x * 4;
    float4 v = *(const float4*)(src + i);
    ushort4 u;
    u.x = bfr(v.x); u.y = bfr(v.y); u.z = bfr(v.z); u.w = bfr(v.w);
    *(ushort4*)(dst + i) = u;
    if (threadIdx.x == 0) bias2[c] = bias[o];
}

// ---------------------------------------------------------------------------
// Fused per-chunk kernel.
//  blocks [0,32): scan of chunk i-1 (projSrc), 512 thr each (16384 lanes)
//  blocks [32, 32+nG): 256x256 8-wave GEMM of chunk i -> projDst
//    BK=32, triple-buffered 96KB LDS, 2-tile staging lead,
//    counted vmcnt(4), one barrier per K-tile.
//  NOTE: 256^2 tile needs ~200 VGPR (acc=128) => 1 block/CU is
//  register-forced; (512,4) occupancy spills catastrophically (r16).
//  Epilogue: wave-local LDS transpose (slot-1 reuse, 144B padded rows,
//  no barriers) -> 16B/lane full-line proj stores (kills RMW fills).
// ---------------------------------------------------------------------------
__global__ __launch_bounds__(512, 2) void fused_chunk(
    const unsigned short* __restrict__ x2,    // [T*32][512] bf16
    const unsigned short* __restrict__ W2,    // [3072][512] bf16 (permuted)
    const float* __restrict__ bias2,          // [3072] (permuted)
    _Float16* __restrict__ projDst,           // [Tcg*32][PW]
    const _Float16* __restrict__ projSrc,     // [Tcs*32][PW]
    const float* __restrict__ h0, const float* __restrict__ s0,
    float* __restrict__ outH, float* __restrict__ outS,
    int t0g, int Tcg, int t0s, int Tcs)
{
    // slot s: A (256x32) at lds + s*16384, B at +8192 (shorts); 96 KB
    __shared__ unsigned short lds[3 * 16384];

    if (blockIdx.x < SCANBLKS) {
        // ------------------------- scan of chunk i-1 -------------------------
        if (t0s < 0) return;
        const int gid = blockIdx.x * 512 + threadIdx.x;   // 0..16383
        const int b   = gid >> 9;
        const int d   = gid & 511;

        float h, s;
        if (t0s == 0) { h = h0[gid]; s = s0[gid]; }
        else {
            h = outH[((size_t)b * TT + (t0s - 1)) * DD + d];
            s = outS[gid];
        }

        const unsigned* pu = (const unsigned*)(projSrc + (size_t)b * PW + d * 2);
        const size_t tstr = (size_t)BB * PW / 2;   // uints per step
        float* oH = outH + ((size_t)b * TT + t0s) * DD + d;

        unsigned bufA[PF][3], bufB[PF][3];
        #pragma unroll
        for (int u = 0; u < PF; ++u)
            #pragma unroll
            for (int p = 0; p < 3; ++p)
                bufA[u][p] = pu[(size_t)u * tstr + p * 512];

        for (int tb = 0; tb < Tcs; tb += 2 * PF) {
            #pragma unroll
            for (int u = 0; u < PF; ++u) {
                int t = tb + PF + u; if (t > Tcs - 1) t = Tcs - 1;
                #pragma unroll
                for (int p = 0; p < 3; ++p)
                    bufB[u][p] = pu[(size_t)t * tstr + p * 512];
            }
            #pragma unroll
            for (int u = 0; u < PF; ++u) {
                float a0 = h2lo(bufA[u][0]), a1 = h2hi(bufA[u][0]);
                float t2 = h2lo(bufA[u][1]), a3 = h2hi(bufA[u][1]);
                float a4 = h2lo(bufA[u][2]), z5 = h2hi(bufA[u][2]);
                s = __builtin_fmaf(a0, s, a1 * t2);
                h = __builtin_fmaf(a3, h, a4 * ftanh(z5 + s));
                oH[(size_t)(tb + u) * DD] = h;
            }
            #pragma unroll
            for (int u = 0; u < PF; ++u) {
                int t = tb + 2 * PF + u; if (t > Tcs - 1) t = Tcs - 1;
                #pragma unroll
                for (int p = 0; p < 3; ++p)
                    bufA[u][p] = pu[(size_t)t * tstr + p * 512];
            }
            #pragma unroll
            for (int u = 0; u < PF; ++u) {
                float a0 = h2lo(bufB[u][0]), a1 = h2hi(bufB[u][0]);
                float t2 = h2lo(bufB[u][1]), a3 = h2hi(bufB[u][1]);
                float a4 = h2lo(bufB[u][2]), z5 = h2hi(bufB[u][2]);
                s = __builtin_fmaf(a0, s, a1 * t2);
                h = __builtin_fmaf(a3, h, a4 * ftanh(z5 + s));
                oH[(size_t)(tb + PF + u) * DD] = h;
            }
        }
        outS[gid] = s;
        return;
    }

    // ----------------------------- GEMM of chunk i ---------------------------
    if (t0g < 0) return;
    const unsigned nwg = gridDim.x - SCANBLKS;
    const unsigned fb  = blockIdx.x - SCANBLKS;
    const unsigned qq  = nwg >> 3, rr8 = nwg & 7;
    const unsigned xcd = fb & 7, sid = fb >> 3;
    const unsigned work = (xcd < rr8 ? xcd * (qq + 1)
                                     : rr8 * (qq + 1) + (xcd - rr8) * qq) + sid;
    const int bx = (int)(work % (NN / BNT));    // 12 col tiles
    const int by = (int)(work / (NN / BNT));

    const int tid  = threadIdx.x;
    const int row0 = by * BMT;                  // chunk-local
    const int col0 = bx * BNT;
    const size_t growA = (size_t)t0g * BB + row0;

    const int lane = tid & 63;
    const int wv   = tid >> 6;       // 0..7
    const int wm   = wv >> 2;        // 0..1  (M half)
    const int wn   = wv & 3;         // 0..3  (N quarter)
    const int lr   = lane & 15;
    const int lq   = lane >> 4;

    auto stageA = [&](int s, int kt) {
        unsigned short* Ab = lds + s * 16384;
        const int k0 = kt * BKT;
        #pragma unroll
        for (int a = 0; a < 2; ++a) {
            int cid = a * 512 + tid;        // 0..1023
            int rt  = cid >> 2;             // row
            int cp  = cid & 3;              // 16B chunk in row
            gl2lds16(x2 + (growA + rt) * DIN + k0 + cp * 8, Ab + cid * 8);
        }
    };
    auto stageB = [&](int s, int kt) {
        unsigned short* Bb = lds + s * 16384 + 8192;
        const int k0 = kt * BKT;
        #pragma unroll
        for (int a = 0; a < 2; ++a) {
            int cid = a * 512 + tid;
            int rt  = cid >> 2;
            int cp  = cid & 3;
            gl2lds16(W2 + (size_t)(col0 + rt) * DIN + k0 + cp * 8, Bb + cid * 8);
        }
    };

    f32x4 acc[8][4] = {};

    stageA(0, 0); stageB(0, 0);
    stageA(1, 1); stageB(1, 1);
    asm volatile("s_waitcnt vmcnt(4)" ::: "memory");
    __builtin_amdgcn_s_barrier();

    #pragma unroll
    for (int kt = 0; kt < NKT; ++kt) {
        const unsigned short* Ab = lds + (kt % 3) * 16384;
        const unsigned short* Bb = Ab + 8192;
        const bool st = (kt + 2) < NKT;

        if (st) { stageA((kt + 2) % 3, kt + 2); stageB((kt + 2) % 3, kt + 2); }

        s16x8 bv[4], av[8];
        #pragma unroll
        for (int j = 0; j < 4; ++j) {
            int col = wn * 64 + j * 16 + lr;
            bv[j] = *(const s16x8*)(Bb + col * BKT + lq * 8);
        }
        #pragma unroll
        for (int m = 0; m < 8; ++m) {
            int row = wm * 128 + m * 16 + lr;
            av[m] = *(const s16x8*)(Ab + row * BKT + lq * 8);
        }

        __builtin_amdgcn_s_setprio(1);
        #pragma unroll
        for (int m = 0; m < 8; ++m)
            #pragma unroll
            for (int j = 0; j < 4; ++j)
                acc[m][j] = __builtin_amdgcn_mfma_f32_16x16x32_bf16(
                    bv[j], av[m], acc[m][j], 0, 0, 0);
        __builtin_amdgcn_s_setprio(0);

        if (kt + 1 < NKT) {
            if (st) asm volatile("s_waitcnt vmcnt(4)" ::: "memory");
            else    asm volatile("s_waitcnt vmcnt(0)" ::: "memory");
            __builtin_amdgcn_s_barrier();
        }
    }

    // ---- epilogue: bias + activation, wave-local LDS transpose, ----
    // ---- 16B/lane full-line stores (8 lanes cover a 128B row line) ----
    // Slot-1 reuse is safe: last used kt=13; post-kt-14 barrier passed.
    const int p = col0 >> 10;
    const bool evenTanh = (p == 1);
    const bool oddIdent = (p == 2);
    const float mEven = evenTanh ? 2.885390082f : -1.442695041f;

    char* epi = (char*)lds + 32768 + wv * 2304;   // 16 rows x 144 B
    const int colw = col0 + wn * 64;
    const int l8 = lane & 7, lh = lane >> 3;

    #pragma unroll
    for (int m = 0; m < 8; ++m) {
        // compute + write 8B per j into this wave's private slot
        #pragma unroll
        for (int j = 0; j < 4; ++j) {
            float4 bc = *(const float4*)(bias2 + colw + j * 16 + lq * 4);
            float z0 = acc[m][j][0] + bc.x;
            float z1 = acc[m][j][1] + bc.y;
            float z2 = acc[m][j][2] + bc.z;
            float z3 = acc[m][j][3] + bc.w;
            float e0 = __builtin_amdgcn_rcpf(1.f + __builtin_amdgcn_exp2f(z0 * mEven));
            float e2 = __builtin_amdgcn_rcpf(1.f + __builtin_amdgcn_exp2f(z2 * mEven));
            float v0 = evenTanh ? (1.f - 2.f * e0) : e0;
            float v2 = evenTanh ? (1.f - 2.f * e2) : e2;
            float v1 = oddIdent ? z1
                : __builtin_amdgcn_rcpf(1.f + __builtin_amdgcn_exp2f(z1 * -1.442695041f));
            float v3 = oddIdent ? z3
                : __builtin_amdgcn_rcpf(1.f + __builtin_amdgcn_exp2f(z3 * -1.442695041f));
            ushort4 o;
            o.x = __builtin_bit_cast(unsigned short, (_Float16)v0);
            o.y = __builtin_bit_cast(unsigned short, (_Float16)v1);
            o.z = __builtin_bit_cast(unsigned short, (_Float16)v2);
            o.w = __builtin_bit_cast(unsigned short, (_Float16)v3);
            *(ushort4*)(epi + lr * 144 + j * 32 + lq * 8) = o;
        }
        // read back row-contiguous, store 16B/lane (compiler inserts lgkmcnt)
        #pragma unroll
        for (int hh = 0; hh < 2; ++hh) {
            int rr = hh * 8 + lh;
            uint4 v = *(const uint4*)(epi + rr * 144 + l8 * 16);
            int g = row0 + wm * 128 + m * 16 + rr;
            *(uint4*)((char*)projDst + ((size_t)g * PW + colw + l8 * 8) * 2) = v;
        }
    }
}

// ---------------------------------------------------------------------------
extern "C" void kernel_launch(void* const* d_in, const int* in_sizes, int n_in,
                              void* d_out, int out_size, void* d_ws, size_t ws_size,
                              hipStream_t stream) {
    const float* x    = (const float*)d_in[0];
    const float* h0   = (const float*)d_in[1];
    const float* s0   = (const float*)d_in[2];
    const float* W    = (const float*)d_in[3];
    const float* bias = (const float*)d_in[4];

    float* outH = (float*)d_out;
    float* outS = outH + (size_t)BB * TT * DD;

    char* ws = (char*)d_ws;
    const size_t x2_bytes = (size_t)BB * TT * DIN * 2;       // 64 MB
    const size_t w2_bytes = (size_t)NN * DIN * 2;            // 3 MB
    const size_t b2_bytes = (size_t)NN * 4;
    unsigned short* x2    = (unsigned short*)ws;
    unsigned short* W2    = (unsigned short*)(ws + x2_bytes);
    float*          bias2 = (float*)(ws + x2_bytes + w2_bytes);

    const size_t fixed = x2_bytes + w2_bytes + b2_bytes;
    const size_t per_t = (size_t)BB * PW * 2;                // 192 KB / step
    size_t avail = ws_size > fixed ? ws_size - fixed : 0;
    int TcMax = (int)(avail / (2 * per_t));                  // ping-pong proj
    if (TcMax > 512) TcMax = 512;   // keep proj chunk L3-resident
    TcMax &= ~31;                   // multiple of 32 (scan 2*PF, M tile 256)
    if (TcMax < 32) TcMax = 32;

    _Float16* projA = (_Float16*)(ws + fixed);
    _Float16* projB = projA + (size_t)TcMax * BB * PW;

    convert_x<<<2048, 256, 0, stream>>>(x, x2);
    convert_w<<<NN, 128, 0, stream>>>(W, bias, W2, bias2);

    const int nC = (TT + TcMax - 1) / TcMax;
    int prevT0 = -1, prevTc = 0;
    const _Float16* prevProj = nullptr;

    for (int ci = 0; ci <= nC; ++ci) {
        const bool hasG = (ci < nC);
        int t0 = ci * TcMax;
        int Tc = 0;
        _Float16* dst = nullptr;
        int nG = 0;
        if (hasG) {
            Tc  = TT - t0; if (Tc > TcMax) Tc = TcMax;
            dst = (ci & 1) ? projB : projA;
            nG  = (NN / BNT) * (Tc * BB / BMT);
        }
        fused_chunk<<<dim3(SCANBLKS + nG), 512, 0, stream>>>(
            x2, W2, bias2, dst, prevProj, h0, s0, outH, outS,
            hasG ? t0 : -1, Tc, prevT0, prevTc);
        if (hasG) { prevProj = dst; prevT0 = t0; prevTc = Tc; }
    }
}